// Round 1
// baseline (497.967 us; speedup 1.0000x reference)
//
#include <hip/hip_runtime.h>
#include <hip/hip_bf16.h>

#define Bsz 4
#define Nn 2048
#define Dd 512
#define Hh 8
#define HDim 64
#define MTOT (Bsz * Nn)  // 8192

typedef unsigned short ush;
typedef __bf16 bf16x8 __attribute__((ext_vector_type(8)));
typedef float f32x4 __attribute__((ext_vector_type(4)));

__device__ __forceinline__ ush f2bf(float f) {
    unsigned u = __builtin_bit_cast(unsigned, f);
    unsigned r = (u + 0x7fffu + ((u >> 16) & 1u)) >> 16;
    return (ush)r;
}

// ---------------- convert f32 -> bf16 ----------------
__global__ __launch_bounds__(256) void convert_bf16(const float* __restrict__ src,
                                                    ush* __restrict__ dst, int n) {
    int i = (blockIdx.x * 256 + threadIdx.x) * 4;
    if (i < n) {
        float4 v = *reinterpret_cast<const float4*>(src + i);
        dst[i + 0] = f2bf(v.x);
        dst[i + 1] = f2bf(v.y);
        dst[i + 2] = f2bf(v.z);
        dst[i + 3] = f2bf(v.w);
    }
}

// ---------------- generic bf16 GEMM: C = A(MTOTxD) * W(DxD) + bias ----------------
// mode 0: out bf16, layout (B,H,N,HD)  [Q,K]
// mode 1: out bf16, layout (B,H,HD,N)  [V transposed]
// mode 2: out f32, row-major (MTOT x D) [h = O@Wo]
__global__ __launch_bounds__(256) void gemm_bf16(const ush* __restrict__ A,
                                                 const ush* __restrict__ Wb,
                                                 const float* __restrict__ bias,
                                                 int mode, ush* __restrict__ outb,
                                                 float* __restrict__ outf) {
    __shared__ __align__(16) ush As[64][56];
    __shared__ __align__(16) ush Bt[64][56];
    const int t = threadIdx.x;
    const int lane = t & 63, w = t >> 6;
    const int ln = lane & 15, gr = lane >> 4;
    const int m0 = blockIdx.x * 64, n0 = blockIdx.y * 64;

    const int arow = t >> 2, acol = (t & 3) * 8;
    const int krow = t >> 3, bcol = (t & 7) * 8;

    f32x4 acc[4] = {};

    for (int k0 = 0; k0 < Dd; k0 += 32) {
        // stage A tile (64 x 32)
        uint4 av = *reinterpret_cast<const uint4*>(A + (size_t)(m0 + arow) * Dd + k0 + acol);
        *reinterpret_cast<uint4*>(&As[arow][acol]) = av;
        // stage W tile (32 x 64) transposed into Bt[col][k]
        uint4 bv = *reinterpret_cast<const uint4*>(Wb + (size_t)(k0 + krow) * Dd + n0 + bcol);
        ush btmp[8];
        *reinterpret_cast<uint4*>(btmp) = bv;
#pragma unroll
        for (int i = 0; i < 8; ++i) Bt[bcol + i][krow] = btmp[i];
        __syncthreads();

        bf16x8 af = *reinterpret_cast<const bf16x8*>(&As[w * 16 + ln][gr * 8]);
#pragma unroll
        for (int nt = 0; nt < 4; ++nt) {
            bf16x8 bfr = *reinterpret_cast<const bf16x8*>(&Bt[nt * 16 + ln][gr * 8]);
            acc[nt] = __builtin_amdgcn_mfma_f32_16x16x32_bf16(af, bfr, acc[nt], 0, 0, 0);
        }
        __syncthreads();
    }

#pragma unroll
    for (int nt = 0; nt < 4; ++nt) {
#pragma unroll
        for (int r = 0; r < 4; ++r) {
            int row = m0 + w * 16 + gr * 4 + r;   // global m (b*N + n)
            int col = n0 + nt * 16 + ln;          // global d
            float v = acc[nt][r] + bias[col];
            if (mode == 2) {
                outf[(size_t)row * Dd + col] = v;
            } else {
                int b = row >> 11, n = row & (Nn - 1);
                int h = col >> 6, hd = col & 63;
                if (mode == 0)
                    outb[(((size_t)(b * Hh + h)) * Nn + n) * HDim + hd] = f2bf(v);
                else
                    outb[(((size_t)(b * Hh + h)) * HDim + hd) * Nn + n] = f2bf(v);
            }
        }
    }
}

// ---------------- masked flash attention ----------------
// grid: B*H*(N/64) blocks, 256 threads (4 waves); wave w owns 16 q-rows
__global__ __launch_bounds__(256) void attn_kernel(const ush* __restrict__ Q,
                                                   const ush* __restrict__ K,
                                                   const ush* __restrict__ Vt,
                                                   const int* __restrict__ adj,
                                                   ush* __restrict__ O) {
    __shared__ __align__(16) ush Pl[4][16][56];
    const int t = threadIdx.x, lane = t & 63, w = t >> 6;
    const int ln = lane & 15, gr = lane >> 4;
    const int blk = blockIdx.x;
    const int qt = blk & 31;   // N/64 = 32 q-tiles
    const int bh = blk >> 5;   // 0..31
    const int b = bh >> 3, h = bh & 7;
    const int q0 = qt * 64 + w * 16;

    const ush* Qb = Q + (size_t)bh * Nn * HDim;
    const ush* Kb = K + (size_t)bh * Nn * HDim;
    const ush* Vb = Vt + (size_t)bh * HDim * Nn;
    const int* adjb = adj + (size_t)b * Nn * Nn;

    bf16x8 aq0 = *reinterpret_cast<const bf16x8*>(Qb + (size_t)(q0 + ln) * HDim + gr * 8);
    bf16x8 aq1 = *reinterpret_cast<const bf16x8*>(Qb + (size_t)(q0 + ln) * HDim + 32 + gr * 8);

    f32x4 accO[4] = {};
    float mrow[4] = {-1e30f, -1e30f, -1e30f, -1e30f};
    float lrow[4] = {0.f, 0.f, 0.f, 0.f};

    for (int kv0 = 0; kv0 < Nn; kv0 += 32) {
        bf16x8 bk0a = *reinterpret_cast<const bf16x8*>(Kb + (size_t)(kv0 + ln) * HDim + gr * 8);
        bf16x8 bk0b = *reinterpret_cast<const bf16x8*>(Kb + (size_t)(kv0 + ln) * HDim + 32 + gr * 8);
        bf16x8 bk1a = *reinterpret_cast<const bf16x8*>(Kb + (size_t)(kv0 + 16 + ln) * HDim + gr * 8);
        bf16x8 bk1b = *reinterpret_cast<const bf16x8*>(Kb + (size_t)(kv0 + 16 + ln) * HDim + 32 + gr * 8);

        f32x4 s0 = {}, s1 = {};
        s0 = __builtin_amdgcn_mfma_f32_16x16x32_bf16(aq0, bk0a, s0, 0, 0, 0);
        s0 = __builtin_amdgcn_mfma_f32_16x16x32_bf16(aq1, bk0b, s0, 0, 0, 0);
        s1 = __builtin_amdgcn_mfma_f32_16x16x32_bf16(aq0, bk1a, s1, 0, 0, 0);
        s1 = __builtin_amdgcn_mfma_f32_16x16x32_bf16(aq1, bk1b, s1, 0, 0, 0);

#pragma unroll
        for (int r = 0; r < 4; ++r) {
            const int qrow = q0 + gr * 4 + r;
            const int* ar = adjb + (size_t)qrow * Nn + kv0;
            float v0 = s0[r] * 0.125f;
            if (ar[ln] == 0) v0 = -1e30f;
            float v1 = s1[r] * 0.125f;
            if (ar[16 + ln] == 0) v1 = -1e30f;

            float mc = fmaxf(v0, v1);
            mc = fmaxf(mc, __shfl_xor(mc, 1));
            mc = fmaxf(mc, __shfl_xor(mc, 2));
            mc = fmaxf(mc, __shfl_xor(mc, 4));
            mc = fmaxf(mc, __shfl_xor(mc, 8));
            float mn = fmaxf(mrow[r], mc);
            float alpha = __expf(mrow[r] - mn);
            mrow[r] = mn;
            float p0 = __expf(v0 - mn), p1 = __expf(v1 - mn);
            float ps = p0 + p1;
            ps += __shfl_xor(ps, 1);
            ps += __shfl_xor(ps, 2);
            ps += __shfl_xor(ps, 4);
            ps += __shfl_xor(ps, 8);
            lrow[r] = lrow[r] * alpha + ps;
#pragma unroll
            for (int c4 = 0; c4 < 4; ++c4) accO[c4][r] *= alpha;
            Pl[w][gr * 4 + r][ln] = f2bf(p0);
            Pl[w][gr * 4 + r][16 + ln] = f2bf(p1);
        }
        // re-fragment P: A-layout read (same wave; compiler inserts lgkm waits)
        bf16x8 pf = *reinterpret_cast<const bf16x8*>(&Pl[w][ln][gr * 8]);
#pragma unroll
        for (int c4 = 0; c4 < 4; ++c4) {
            bf16x8 vf = *reinterpret_cast<const bf16x8*>(Vb + (size_t)(c4 * 16 + ln) * Nn + kv0 + gr * 8);
            accO[c4] = __builtin_amdgcn_mfma_f32_16x16x32_bf16(pf, vf, accO[c4], 0, 0, 0);
        }
    }

#pragma unroll
    for (int r = 0; r < 4; ++r) {
        int qrow = q0 + gr * 4 + r;
        float inv = 1.0f / lrow[r];
#pragma unroll
        for (int c4 = 0; c4 < 4; ++c4) {
            O[((size_t)(b * Nn + qrow)) * Dd + h * HDim + c4 * 16 + ln] = f2bf(accO[c4][r] * inv);
        }
    }
}

// ---------------- residual + LayerNorm ----------------
__global__ __launch_bounds__(256) void ln_kernel(const float* __restrict__ hbuf,
                                                 const float* __restrict__ x,
                                                 const float* __restrict__ gamma,
                                                 const float* __restrict__ beta,
                                                 float* __restrict__ out) {
    const int row = blockIdx.x;
    const int t = threadIdx.x;
    const float* hr = hbuf + (size_t)row * Dd;
    const float* xr = x + (size_t)row * Dd;
    float y0 = hr[t] + xr[t];
    float y1 = hr[t + 256] + xr[t + 256];

    __shared__ float red[4];
    float s = y0 + y1;
#pragma unroll
    for (int m = 32; m; m >>= 1) s += __shfl_xor(s, m);
    if ((t & 63) == 0) red[t >> 6] = s;
    __syncthreads();
    float mu = (red[0] + red[1] + red[2] + red[3]) * (1.0f / Dd);

    float d0 = y0 - mu, d1 = y1 - mu;
    float vs = d0 * d0 + d1 * d1;
#pragma unroll
    for (int m = 32; m; m >>= 1) vs += __shfl_xor(vs, m);
    __syncthreads();
    if ((t & 63) == 0) red[t >> 6] = vs;
    __syncthreads();
    float var = (red[0] + red[1] + red[2] + red[3]) * (1.0f / Dd);
    float rs = rsqrtf(var + 1e-5f);

    out[(size_t)row * Dd + t] = d0 * rs * gamma[t] + beta[t];
    out[(size_t)row * Dd + t + 256] = d1 * rs * gamma[t + 256] + beta[t + 256];
}

extern "C" void kernel_launch(void* const* d_in, const int* in_sizes, int n_in,
                              void* d_out, int out_size, void* d_ws, size_t ws_size,
                              hipStream_t stream) {
    const float* x = (const float*)d_in[0];
    const int* adj = (const int*)d_in[1];
    const float* Wq = (const float*)d_in[2];
    const float* bq = (const float*)d_in[3];
    const float* Wk = (const float*)d_in[4];
    const float* bk = (const float*)d_in[5];
    const float* Wv = (const float*)d_in[6];
    const float* bv = (const float*)d_in[7];
    const float* Wo = (const float*)d_in[8];
    const float* bo = (const float*)d_in[9];
    const float* gamma = (const float*)d_in[10];
    const float* beta = (const float*)d_in[11];
    float* out = (float*)d_out;

    const size_t MD = (size_t)MTOT * Dd;  // 4194304
    const size_t WW = (size_t)Dd * Dd;    // 262144
    ush* ws = (ush*)d_ws;
    ush* xb = ws;
    ush* Wqb = xb + MD;
    ush* Wkb = Wqb + WW;
    ush* Wvb = Wkb + WW;
    ush* Wob = Wvb + WW;
    ush* Qb = Wob + WW;
    ush* Kb = Qb + MD;
    ush* Vtb = Kb + MD;
    ush* Ob = Vtb + MD;
    float* hbuf = (float*)(Ob + MD);

    convert_bf16<<<dim3((int)(MD / 1024)), dim3(256), 0, stream>>>(x, xb, (int)MD);
    convert_bf16<<<dim3((int)(WW / 1024)), dim3(256), 0, stream>>>(Wq, Wqb, (int)WW);
    convert_bf16<<<dim3((int)(WW / 1024)), dim3(256), 0, stream>>>(Wk, Wkb, (int)WW);
    convert_bf16<<<dim3((int)(WW / 1024)), dim3(256), 0, stream>>>(Wv, Wvb, (int)WW);
    convert_bf16<<<dim3((int)(WW / 1024)), dim3(256), 0, stream>>>(Wo, Wob, (int)WW);

    dim3 gg(MTOT / 64, Dd / 64), bb(256);
    gemm_bf16<<<gg, bb, 0, stream>>>(xb, Wqb, bq, 0, Qb, nullptr);
    gemm_bf16<<<gg, bb, 0, stream>>>(xb, Wkb, bk, 0, Kb, nullptr);
    gemm_bf16<<<gg, bb, 0, stream>>>(xb, Wvb, bv, 1, Vtb, nullptr);

    attn_kernel<<<dim3(Bsz * Hh * (Nn / 64)), bb, 0, stream>>>(Qb, Kb, Vtb, adj, Ob);

    gemm_bf16<<<gg, bb, 0, stream>>>(Ob, Wob, bo, 2, nullptr, hbuf);

    ln_kernel<<<dim3(MTOT), bb, 0, stream>>>(hbuf, x, gamma, beta, out);
}